// Round 2
// baseline (2580.382 us; speedup 1.0000x reference)
//
#include <hip/hip_runtime.h>
#include <math.h>

// ---------------------------------------------------------------------------
// SetOnlyLM forward on MI355X — round 2.
//   - All GEMMs: MFMA bf16 hi/lo split (3 MFMAs / tile-pair), ~fp32 accuracy.
//   - NEW: head GEMM (85% of FLOPs) runs on a bf16-plane path: h and head_w
//     are pre-split into bf16 hi/lo planes once, then staged via
//     global_load_lds width=16 into linear [128][32] LDS tiles (m97
//     structure, no per-block conversion VALU). Runtime ws_size guard falls
//     back to the fp32-staging GEMM if scratch is too small.
//   - Layer stack (126-row GEMMs, band attention) unchanged from round 1.
// ---------------------------------------------------------------------------

#define D      1024
#define DFF    4096
#define NSETS  63
#define BROWS  126        // B * NSETS
#define SEQLEN 2048
#define NTOK   4096       // B * SEQLEN
#define VOCAB  32000

typedef float f32x4 __attribute__((ext_vector_type(4)));
typedef short s16x4 __attribute__((ext_vector_type(4)));
typedef short s16x8 __attribute__((ext_vector_type(8)));

// ---- fp32 -> bf16 (RNE) and hi/lo split -----------------------------------
__device__ __forceinline__ short bf16_rne(float x, float& back) {
  unsigned u = __builtin_bit_cast(unsigned, x);
  unsigned r = (u + 0x7fffu + ((u >> 16) & 1u)) & 0xffff0000u;
  back = __builtin_bit_cast(float, r);
  return (short)(r >> 16);
}
__device__ __forceinline__ void split2(float x, short& h, short& l) {
  float hf;
  h = bf16_rne(x, hf);
  float rest = x - hf;          // exact in fp32 (|rest| <= 2^-9 |x|)
  float dummy;
  l = bf16_rne(rest, dummy);
}

__device__ __forceinline__ float gelu_exact(float x) {
  return 0.5f * x * (1.0f + erff(x * 0.70710678118654752f));
}

// async global->LDS, 16 B per lane; LDS dest is wave-uniform base + lane*16
__device__ __forceinline__ void gload16(const void* g, void* l) {
  __builtin_amdgcn_global_load_lds(
      (const __attribute__((address_space(1))) unsigned int*)g,
      (__attribute__((address_space(3))) unsigned int*)l,
      16, 0, 0);
}

// ---- staging helpers (fp32 inputs, convert on the fly) ---------------------
// NT: src is [rows][ld] row-major, stage rows row0..row0+127, cols kt..kt+31
template<bool SPLIT>
__device__ __forceinline__ void stage_nt(const float* __restrict__ src, int row0,
                                         int nrows, int ld, int kt,
                                         short (*th)[40], short (*tl)[40], int tid) {
#pragma unroll
  for (int j = 0; j < 4; ++j) {
    int f = tid + 256 * j;        // float4 slot in [128][8]
    int r = f >> 3, c4 = f & 7;
    int gr = row0 + r;
    f32x4 val = {0.f, 0.f, 0.f, 0.f};
    if (gr < nrows) val = *(const f32x4*)(src + (long)gr * ld + kt + c4 * 4);
    s16x4 h4, l4;
#pragma unroll
    for (int e = 0; e < 4; ++e) {
      short hh, ll;
      if (SPLIT) { split2(val[e], hh, ll); }
      else { float bk; hh = bf16_rne(val[e], bk); ll = 0; }
      h4[e] = hh; l4[e] = ll;
    }
    *(s16x4*)&th[r][c4 * 4] = h4;
    if (SPLIT) *(s16x4*)&tl[r][c4 * 4] = l4;
  }
}

// NN: src is [K][ld] row-major; stage cols col0..col0+127, rows kt..kt+31,
// transposed into tile [n][k]. Each thread owns one n and a 16-deep k column.
template<bool SPLIT>
__device__ __forceinline__ void stage_nn(const float* __restrict__ src, int col0,
                                         int ld, int kt,
                                         short (*th)[40], short (*tl)[40], int tid) {
  int n = tid & 127;
  int kb = (tid >> 7) * 16;
  const float* p = src + (long)(kt + kb) * ld + col0 + n;
  float v[16];
#pragma unroll
  for (int i = 0; i < 16; ++i) v[i] = p[(long)i * ld];
#pragma unroll
  for (int half = 0; half < 2; ++half) {
    s16x8 h8, l8;
#pragma unroll
    for (int e = 0; e < 8; ++e) {
      short hh, ll;
      if (SPLIT) { split2(v[half * 8 + e], hh, ll); }
      else { float bk; hh = bf16_rne(v[half * 8 + e], bk); ll = 0; }
      h8[e] = hh; l8[e] = ll;
    }
    *(s16x8*)&th[n][kb + half * 8] = h8;
    if (SPLIT) *(s16x8*)&tl[n][kb + half * 8] = l8;
  }
}

// ---- generic GEMM (fp32 inputs, on-the-fly split) --------------------------
// C[M][N] = A[M][K] * B, A row-major [M][lda].
// B_NT: B is [N][ldb] (row n = weight row, dot along K)  -> head_w fallback
// !B_NT: B is [K][ldb] (standard W[k][n])                -> all other weights
// grid: (mblocks, nblocks, ksplit). If ksplit>1, EPI must be 0 and partials are
// written at C + z*part_stride.  EPI: 0 none, 1 +bias, 2 gelu(x+bias)
template<bool B_NT, int EPI, bool SPLIT>
__global__ __launch_bounds__(256) void gemm_k(
    const float* __restrict__ A, const float* __restrict__ Bm,
    const float* __restrict__ bias, float* __restrict__ C,
    int M, int N, int K, int lda, int ldb, int ldc, long part_stride) {
  __shared__ short Ah[128][40];
  __shared__ short Bh[128][40];
  __shared__ short Al[SPLIT ? 128 : 1][40];
  __shared__ short Bl[SPLIT ? 128 : 1][40];

  const int tid = threadIdx.x;
  const int lane = tid & 63, wid = tid >> 6;
  const int wr = (wid >> 1) * 64, wc = (wid & 1) * 64;
  const int row0 = blockIdx.x * 128, col0 = blockIdx.y * 128;
  const int kchunk = K / gridDim.z;
  const int k0 = blockIdx.z * kchunk;

  f32x4 acc[4][4] = {};

  for (int kt = k0; kt < k0 + kchunk; kt += 32) {
    stage_nt<SPLIT>(A, row0, M, lda, kt, Ah, Al, tid);
    if (B_NT) stage_nt<SPLIT>(Bm, col0, N, ldb, kt, Bh, Bl, tid);
    else      stage_nn<SPLIT>(Bm, col0, ldb, kt, Bh, Bl, tid);
    __syncthreads();

    const int am = wr + (lane & 15);
    const int bn = wc + (lane & 15);
    const int kq = (lane >> 4) * 8;
    s16x8 ah[4], al[4], bh[4], bl[4];
#pragma unroll
    for (int i = 0; i < 4; ++i) {
      ah[i] = *(const s16x8*)&Ah[am + i * 16][kq];
      bh[i] = *(const s16x8*)&Bh[bn + i * 16][kq];
      if (SPLIT) {
        al[i] = *(const s16x8*)&Al[am + i * 16][kq];
        bl[i] = *(const s16x8*)&Bl[bn + i * 16][kq];
      }
    }
#pragma unroll
    for (int mi = 0; mi < 4; ++mi)
#pragma unroll
      for (int ni = 0; ni < 4; ++ni) {
        acc[mi][ni] = __builtin_amdgcn_mfma_f32_16x16x32_bf16(ah[mi], bh[ni], acc[mi][ni], 0, 0, 0);
        if (SPLIT) {
          acc[mi][ni] = __builtin_amdgcn_mfma_f32_16x16x32_bf16(ah[mi], bl[ni], acc[mi][ni], 0, 0, 0);
          acc[mi][ni] = __builtin_amdgcn_mfma_f32_16x16x32_bf16(al[mi], bh[ni], acc[mi][ni], 0, 0, 0);
        }
      }
    __syncthreads();
  }

  float* Cb = C + (gridDim.z > 1 ? (long)blockIdx.z * part_stride : 0);
#pragma unroll
  for (int mi = 0; mi < 4; ++mi)
#pragma unroll
    for (int ni = 0; ni < 4; ++ni) {
      int c = col0 + wc + ni * 16 + (lane & 15);
#pragma unroll
      for (int r = 0; r < 4; ++r) {
        int m = row0 + wr + mi * 16 + (lane >> 4) * 4 + r;
        if (m < M) {
          float v = acc[mi][ni][r];
          if (EPI >= 1) v += bias[c];
          if (EPI == 2) v = gelu_exact(v);
          Cb[(long)m * ldc + c] = v;
        }
      }
    }
}

// ---- head GEMM on pre-split bf16 planes (m97 structure) --------------------
// C[4096][VOCAB] = A[4096][1024] @ B[VOCAB][1024]^T
// Ahg/Alg: hi/lo planes of A; Bhg/Blg: hi/lo planes of B. All [rows][1024] bf16.
// Staging: wave w fills plane w of lds via 8 global_load_lds (16 B/lane) —
// linear [128][32] tile, no VGPR roundtrip, no conversion VALU.
__global__ __launch_bounds__(256) void gemm_head_k(
    const short* __restrict__ Ahg, const short* __restrict__ Alg,
    const short* __restrict__ Bhg, const short* __restrict__ Blg,
    float* __restrict__ C) {
  __shared__ short lds[4][128][32];        // Ah, Al, Bh, Bl planes, 32 KiB
  const int tid = threadIdx.x;
  const int lane = tid & 63, wid = tid >> 6;
  const int wr = (wid >> 1) * 64, wc = (wid & 1) * 64;
  const int row0 = blockIdx.x * 128, col0 = blockIdx.y * 128;

  const short* gp;
  int rbase;
  if      (wid == 0) { gp = Ahg; rbase = row0; }
  else if (wid == 1) { gp = Alg; rbase = row0; }
  else if (wid == 2) { gp = Bhg; rbase = col0; }
  else               { gp = Blg; rbase = col0; }
  short* lbase = &lds[wid][0][0];
  const int lrow = lane >> 2;              // 16 rows per issue
  const int lcol = (lane & 3) * 8;         // 8 bf16 = 16 B per lane

  f32x4 acc[4][4] = {};

  for (int kt = 0; kt < D; kt += 32) {
    // stage: 8 issues x 1 KiB per wave -> this wave's 8 KiB plane
    const short* src = gp + (long)(rbase + lrow) * D + kt + lcol;
#pragma unroll
    for (int j = 0; j < 8; ++j)
      gload16(src + (long)j * 16 * D, lbase + j * 512);
    __syncthreads();                        // drains vmcnt before barrier

    const int am = wr + (lane & 15);
    const int bn = wc + (lane & 15);
    const int kq = (lane >> 4) * 8;
    s16x8 ah[4], al[4], bh[4], bl[4];
#pragma unroll
    for (int i = 0; i < 4; ++i) {
      ah[i] = *(const s16x8*)&lds[0][am + i * 16][kq];
      al[i] = *(const s16x8*)&lds[1][am + i * 16][kq];
      bh[i] = *(const s16x8*)&lds[2][bn + i * 16][kq];
      bl[i] = *(const s16x8*)&lds[3][bn + i * 16][kq];
    }
#pragma unroll
    for (int mi = 0; mi < 4; ++mi)
#pragma unroll
      for (int ni = 0; ni < 4; ++ni) {
        acc[mi][ni] = __builtin_amdgcn_mfma_f32_16x16x32_bf16(ah[mi], bh[ni], acc[mi][ni], 0, 0, 0);
        acc[mi][ni] = __builtin_amdgcn_mfma_f32_16x16x32_bf16(ah[mi], bl[ni], acc[mi][ni], 0, 0, 0);
        acc[mi][ni] = __builtin_amdgcn_mfma_f32_16x16x32_bf16(al[mi], bh[ni], acc[mi][ni], 0, 0, 0);
      }
    __syncthreads();
  }

#pragma unroll
  for (int mi = 0; mi < 4; ++mi)
#pragma unroll
    for (int ni = 0; ni < 4; ++ni) {
      int c = col0 + wc + ni * 16 + (lane & 15);
#pragma unroll
      for (int r = 0; r < 4; ++r) {
        int m = row0 + wr + mi * 16 + (lane >> 4) * 4 + r;
        C[(long)m * VOCAB + c] = acc[mi][ni][r];
      }
    }
}

// split fp32 array into bf16 hi/lo planes; one f32x4 per thread
__global__ __launch_bounds__(256) void split_k(const float* __restrict__ in,
                                               short* __restrict__ hi,
                                               short* __restrict__ lo) {
  long idx = (long)blockIdx.x * 256 + threadIdx.x;
  f32x4 v = ((const f32x4*)in)[idx];
  s16x4 h4, l4;
#pragma unroll
  for (int e = 0; e < 4; ++e) {
    short hh, ll;
    split2(v[e], hh, ll);
    h4[e] = hh; l4[e] = ll;
  }
  ((s16x4*)hi)[idx] = h4;
  ((s16x4*)lo)[idx] = l4;
}

// ---- elementwise / small kernels ------------------------------------------
__global__ __launch_bounds__(256) void embed_k(const int* __restrict__ ids,
                                               const float* __restrict__ te,
                                               const float* __restrict__ pe,
                                               float* __restrict__ out) {
  int t = blockIdx.x;                 // 0..4095
  int tt = t & (SEQLEN - 1);
  int id = ids[t];
  int c = threadIdx.x * 4;
  f32x4 e = *(const f32x4*)(te + (long)id * D + c);
  f32x4 p = *(const f32x4*)(pe + (long)tt * D + c);
  e = e + p;
  *(f32x4*)(out + (long)t * D + c) = e;
}

__global__ __launch_bounds__(256) void pool_k(const float* __restrict__ tok,
                                              float* __restrict__ sets) {
  int bs = blockIdx.x;                // 0..125
  int b = bs / NSETS, s = bs - b * NSETS;
  const float* base = tok + ((long)b * SEQLEN + s * 32) * D + threadIdx.x * 4;
  f32x4 acc = {0.f, 0.f, 0.f, 0.f};
#pragma unroll 8
  for (int w = 0; w < 64; ++w) acc = acc + *(const f32x4*)(base + (long)w * D);
  acc = acc * (1.0f / 64.0f);
  *(f32x4*)(sets + (long)bs * D + threadIdx.x * 4) = acc;
}

__global__ __launch_bounds__(256) void ln_k(const float* __restrict__ in,
                                            float* __restrict__ out,
                                            const float* __restrict__ g,
                                            const float* __restrict__ b) {
  int r = blockIdx.x;
  int tid = threadIdx.x;
  int lane = tid & 63, wid = tid >> 6;
  __shared__ float red[4];
  __shared__ float mv[2];
  f32x4 x = *(const f32x4*)(in + (long)r * D + tid * 4);
  float s = x[0] + x[1] + x[2] + x[3];
  for (int o = 32; o > 0; o >>= 1) s += __shfl_down(s, o);
  if (lane == 0) red[wid] = s;
  __syncthreads();
  if (tid == 0) mv[0] = (red[0] + red[1] + red[2] + red[3]) * (1.0f / D);
  __syncthreads();
  float m = mv[0];
  float q = 0;
#pragma unroll
  for (int e = 0; e < 4; ++e) { float d = x[e] - m; q += d * d; }
  for (int o = 32; o > 0; o >>= 1) q += __shfl_down(q, o);
  __syncthreads();
  if (lane == 0) red[wid] = q;
  __syncthreads();
  if (tid == 0) mv[1] = (red[0] + red[1] + red[2] + red[3]) * (1.0f / D);
  __syncthreads();
  float inv = 1.0f / sqrtf(mv[1] + 1e-5f);
  f32x4 gg = *(const f32x4*)(g + tid * 4);
  f32x4 bb = *(const f32x4*)(b + tid * 4);
  f32x4 o4;
#pragma unroll
  for (int e = 0; e < 4; ++e) o4[e] = (x[e] - m) * inv * gg[e] + bb[e];
  *(f32x4*)(out + (long)r * D + tid * 4) = o4;
}

// band attention over 63 sets, one block per (b, head); reduces qkv k-partials
__global__ __launch_bounds__(256) void attn_k(const float* __restrict__ qkvp,
                                              float* __restrict__ o, int nkc) {
  int bh = blockIdx.x;                // 0..31
  int b = bh >> 4, hh = bh & 15;
  int tid = threadIdx.x;
  __shared__ float q[NSETS][64], k[NSETS][64], v[NSETS][64];
  __shared__ float att[NSETS][9];
  const long PS = (long)BROWS * 3072;
  for (int idx = tid; idx < NSETS * 64; idx += 256) {
    int s = idx >> 6, d = idx & 63;
    long base = (long)(b * NSETS + s) * 3072 + hh * 64 + d;
    float sq = 0, sk = 0, sv = 0;
    for (int kc = 0; kc < nkc; ++kc) {
      const float* p = qkvp + kc * PS + base;
      sq += p[0]; sk += p[1024]; sv += p[2048];
    }
    q[s][d] = sq; k[s][d] = sk; v[s][d] = sv;
  }
  __syncthreads();
  for (int idx = tid; idx < NSETS * 9; idx += 256) {
    int s = idx / 9, j = idx - s * 9, t = s - 4 + j;
    float sc = -1e30f;
    if (t >= 0 && t < NSETS) {
      float dot = 0;
      for (int d = 0; d < 64; ++d) dot += q[s][d] * k[t][d];
      sc = dot * 0.125f;               // 1/sqrt(64)
    }
    att[s][j] = sc;
  }
  __syncthreads();
  if (tid < NSETS) {
    float mx = -1e30f;
#pragma unroll
    for (int j = 0; j < 9; ++j) mx = fmaxf(mx, att[tid][j]);
    float e[9], sum = 0;
#pragma unroll
    for (int j = 0; j < 9; ++j) { e[j] = expf(att[tid][j] - mx); sum += e[j]; }
    float inv = 1.0f / sum;
#pragma unroll
    for (int j = 0; j < 9; ++j) att[tid][j] = e[j] * inv;
  }
  __syncthreads();
  for (int idx = tid; idx < NSETS * 64; idx += 256) {
    int s = idx >> 6, d = idx & 63;
    float acc = 0;
#pragma unroll
    for (int j = 0; j < 9; ++j) {
      int t = s - 4 + j;
      if (t >= 0 && t < NSETS) acc += att[s][j] * v[t][d];
    }
    o[(long)(b * NSETS + s) * D + hh * 64 + d] = acc;
  }
}

// dst += sum_kc part[kc] (+bias); float4 granularity
__global__ __launch_bounds__(256) void red_res_k(float* __restrict__ dst,
                                                 const float* __restrict__ part,
                                                 int nkc, long ps4,
                                                 const float* __restrict__ bias,
                                                 int n4, int total4) {
  int idx = blockIdx.x * 256 + threadIdx.x;
  if (idx >= total4) return;
  f32x4 acc = {0.f, 0.f, 0.f, 0.f};
  for (int kc = 0; kc < nkc; ++kc)
    acc = acc + ((const f32x4*)part)[kc * ps4 + idx];
  if (bias) acc = acc + ((const f32x4*)bias)[idx % n4];
  f32x4 d = ((f32x4*)dst)[idx];
  ((f32x4*)dst)[idx] = d + acc;
}

// dst = gelu(sum_kc part[kc] + bias)
__global__ __launch_bounds__(256) void red_bg_k(float* __restrict__ dst,
                                                const float* __restrict__ part,
                                                int nkc, long ps4,
                                                const float* __restrict__ bias,
                                                int n4, int total4) {
  int idx = blockIdx.x * 256 + threadIdx.x;
  if (idx >= total4) return;
  f32x4 acc = {0.f, 0.f, 0.f, 0.f};
  for (int kc = 0; kc < nkc; ++kc)
    acc = acc + ((const f32x4*)part)[kc * ps4 + idx];
  f32x4 bb = ((const f32x4*)bias)[idx % n4];
  f32x4 d;
#pragma unroll
  for (int e = 0; e < 4; ++e) d[e] = gelu_exact(acc[e] + bb[e]);
  ((f32x4*)dst)[idx] = d;
}

// h = tok + mean of covering sets
__global__ __launch_bounds__(256) void router_k(const float* __restrict__ tok,
                                                const float* __restrict__ sets,
                                                float* __restrict__ out) {
  int t = blockIdx.x;                  // 0..4095
  int b = t >> 11, tt = t & (SEQLEN - 1);
  int slo = (tt >= 63) ? ((tt - 32) >> 5) : 0;   // ceil((tt-63)/32), clamped
  int shi = tt >> 5; if (shi > 62) shi = 62;
  float invc = 1.0f / (float)(shi - slo + 1);
  int c = threadIdx.x * 4;
  f32x4 acc = {0.f, 0.f, 0.f, 0.f};
  for (int s = slo; s <= shi; ++s)
    acc = acc + *(const f32x4*)(sets + (long)(b * NSETS + s) * D + c);
  f32x4 tk = *(const f32x4*)(tok + (long)t * D + c);
  acc = tk + acc * invc;
  *(f32x4*)(out + (long)t * D + c) = acc;
}

// ---------------------------------------------------------------------------
extern "C" void kernel_launch(void* const* d_in, const int* in_sizes, int n_in,
                              void* d_out, int out_size, void* d_ws, size_t ws_size,
                              hipStream_t stream) {
  const int*   ids     = (const int*)d_in[0];
  const float* tok_emb = (const float*)d_in[1];
  const float* pos_emb = (const float*)d_in[2];
  const float* mlp_w1  = (const float*)d_in[3];
  const float* mlp_b1  = (const float*)d_in[4];
  const float* mlp_w2  = (const float*)d_in[5];
  const float* mlp_b2  = (const float*)d_in[6];
  const float* ln1_g   = (const float*)d_in[7];
  const float* ln1_b   = (const float*)d_in[8];
  const float* wq      = (const float*)d_in[9];
  const float* wk      = (const float*)d_in[10];
  const float* wv      = (const float*)d_in[11];
  const float* wo      = (const float*)d_in[12];
  const float* ln2_g   = (const float*)d_in[13];
  const float* ln2_b   = (const float*)d_in[14];
  const float* ff_w1   = (const float*)d_in[15];
  const float* ff_b1   = (const float*)d_in[16];
  const float* ff_w2   = (const float*)d_in[17];
  const float* ff_b2   = (const float*)d_in[18];
  const float* head_w  = (const float*)d_in[19];
  float* out = (float*)d_out;

  // ---- workspace layout ----
  // fp32 region: 12,904,448 floats = 51,617,792 B
  float* ws   = (float*)d_ws;
  float* tok  = ws;                         // [4096][1024]
  float* buf2 = tok  + (long)NTOK * D;      // [4096][1024] final h
  float* sets = buf2 + (long)NTOK * D;      // [126][1024]
  float* hbuf = sets + (long)BROWS * D;     // [126][1024]
  float* obuf = hbuf + (long)BROWS * D;     // [126][1024]
  float* tff  = obuf + (long)BROWS * D;     // [126][4096]
  float* qkvp = tff  + (long)BROWS * DFF;   // [4][126][3072]
  float* part = qkvp + 4L * BROWS * 3072;   // max(4*[126][4096], 8*[126][1024])
  float* f32_end = part + 4L * BROWS * DFF;
  // bf16 plane region for the fast head path: 147,849,216 B
  short* hhi = (short*)f32_end;             // [4096][1024] bf16 hi of h
  short* hlo = hhi + (long)NTOK * D;
  short* whi = hlo + (long)NTOK * D;        // [32000][1024] bf16 hi of head_w
  short* wlo = whi + (long)VOCAB * D;
  const size_t ws_needed =
      (size_t)((char*)(wlo + (long)VOCAB * D) - (char*)d_ws);
  const bool fast_head = ws_size >= ws_needed;   // constant across calls

  const long psq  = (long)BROWS * 3072;     // qkv partial stride
  const long pso  = (long)BROWS * 1024;     // 1024-wide partial stride
  const long psf1 = (long)BROWS * 4096;     // ff1 partial stride

  embed_k<<<NTOK, 256, 0, stream>>>(ids, tok_emb, pos_emb, tok);

  // token MLP: buf2 = gelu(tok@w1+b1); tok = buf2@w2+b2
  gemm_k<false, 2, true><<<dim3(32, 8, 1), 256, 0, stream>>>(
      tok, mlp_w1, mlp_b1, buf2, NTOK, D, D, D, D, D, 0);
  gemm_k<false, 1, true><<<dim3(32, 8, 1), 256, 0, stream>>>(
      buf2, mlp_w2, mlp_b2, tok, NTOK, D, D, D, D, D, 0);

  pool_k<<<BROWS, 256, 0, stream>>>(tok, sets);

  for (int l = 0; l < 4; ++l) {
    ln_k<<<BROWS, 256, 0, stream>>>(sets, hbuf, ln1_g + l * D, ln1_b + l * D);
    gemm_k<false, 0, true><<<dim3(1, 8, 4), 256, 0, stream>>>(
        hbuf, wq + (long)l * D * D, nullptr, qkvp + 0,    BROWS, D, D, D, D, 3072, psq);
    gemm_k<false, 0, true><<<dim3(1, 8, 4), 256, 0, stream>>>(
        hbuf, wk + (long)l * D * D, nullptr, qkvp + 1024, BROWS, D, D, D, D, 3072, psq);
    gemm_k<false, 0, true><<<dim3(1, 8, 4), 256, 0, stream>>>(
        hbuf, wv + (long)l * D * D, nullptr, qkvp + 2048, BROWS, D, D, D, D, 3072, psq);
    attn_k<<<32, 256, 0, stream>>>(qkvp, obuf, 4);
    gemm_k<false, 0, true><<<dim3(1, 8, 4), 256, 0, stream>>>(
        obuf, wo + (long)l * D * D, nullptr, part, BROWS, D, D, D, D, D, pso);
    red_res_k<<<(BROWS * D / 4 + 255) / 256, 256, 0, stream>>>(
        sets, part, 4, pso / 4, nullptr, D / 4, BROWS * D / 4);
    ln_k<<<BROWS, 256, 0, stream>>>(sets, hbuf, ln2_g + l * D, ln2_b + l * D);
    gemm_k<false, 0, true><<<dim3(1, 32, 4), 256, 0, stream>>>(
        hbuf, ff_w1 + (long)l * D * DFF, nullptr, part, BROWS, DFF, D, D, DFF, DFF, psf1);
    red_bg_k<<<(BROWS * DFF / 4 + 255) / 256, 256, 0, stream>>>(
        tff, part, 4, psf1 / 4, ff_b1 + l * DFF, DFF / 4, BROWS * DFF / 4);
    gemm_k<false, 0, true><<<dim3(1, 8, 8), 256, 0, stream>>>(
        tff, ff_w2 + (long)l * DFF * D, nullptr, part, BROWS, D, DFF, DFF, D, D, pso);
    red_res_k<<<(BROWS * D / 4 + 255) / 256, 256, 0, stream>>>(
        sets, part, 8, pso / 4, ff_b2 + l * D, D / 4, BROWS * D / 4);
  }

  router_k<<<NTOK, 256, 0, stream>>>(tok, sets, buf2);

  // head: out = h @ head_w^T
  if (fast_head) {
    split_k<<<NTOK * D / 4 / 256, 256, 0, stream>>>(buf2, hhi, hlo);
    split_k<<<VOCAB * D / 4 / 256, 256, 0, stream>>>(head_w, whi, wlo);
    // grid.x = m-blocks: consecutive blocks share the same W n-panel in L2.
    gemm_head_k<<<dim3(32, VOCAB / 128, 1), 256, 0, stream>>>(
        hhi, hlo, whi, wlo, out);
  } else {
    gemm_k<true, 0, true><<<dim3(32, VOCAB / 128, 1), 256, 0, stream>>>(
        buf2, head_w, nullptr, out, NTOK, VOCAB, D, D, D, VOCAB, 0);
  }
}